// Round 9
// baseline (84.119 us; speedup 1.0000x reference)
//
#include <hip/hip_runtime.h>
#include <math.h>

#define EPSD 1e-9

// Odd-even transposition sort of (x,y) pairs by x (tie: y), K passes.
template<int K>
__device__ __forceinline__ void sortxy(double (&x)[K], double (&y)[K]) {
#pragma unroll
    for (int r = 0; r < K; r++) {
#pragma unroll
        for (int j = (r & 1); j + 1 < K; j += 2) {
            bool sw = (x[j] > x[j + 1]) || ((x[j] == x[j + 1]) && (y[j] > y[j + 1]));
            double tx = x[j], ty = y[j];
            x[j] = sw ? x[j + 1] : tx;
            y[j] = sw ? y[j + 1] : ty;
            x[j + 1] = sw ? tx : x[j + 1];
            y[j + 1] = sw ? ty : y[j + 1];
        }
    }
}

// Andrew monotone chain on points sorted by (x,y). CCW hull. (r8 verbatim:
// top-2 register stack, deeper stack per-thread LDS stride 64.)
// On return: Hb[0..m-1] (slot j at Hb[j*64]) = hull CCW from leftmost, m >= 2.
template<int K>
__device__ __forceinline__ int chain_hull(const double (&sx)[K], const double (&sy)[K],
                                          double2* Hb) {
    int k = 0;
    double t1x = 0.0, t1y = 0.0, t2x = 0.0, t2y = 0.0;
#define PUSH_(PX, PY)                                                         \
    {                                                                         \
        if (k >= 2) Hb[(k - 2) * 64] = make_double2(t2x, t2y);                \
        t2x = t1x; t2y = t1y; t1x = (PX); t1y = (PY); k++;                    \
    }
#define POPS_(PX, PY, LIM)                                                    \
    while (k >= (LIM) &&                                                      \
           ((t1x - t2x) * ((PY) - t2y) - (t1y - t2y) * ((PX) - t2x)) <= 0.0) {\
        k--;                                                                  \
        t1x = t2x; t1y = t2y;                                                 \
        if (k >= 2) { double2 v_ = Hb[(k - 2) * 64]; t2x = v_.x; t2y = v_.y; }\
    }
#pragma unroll
    for (int i = 0; i < K; i++) {          // lower chain
        double px = sx[i], py = sy[i];
        POPS_(px, py, 2);
        PUSH_(px, py);
    }
    const int lim = k + 1;
#pragma unroll
    for (int i = K - 2; i >= 0; i--) {     // upper chain
        double px = sx[i], py = sy[i];
        POPS_(px, py, lim);
        PUSH_(px, py);
    }
#undef PUSH_
#undef POPS_
    if (k >= 2) Hb[(k - 2) * 64] = make_double2(t2x, t2y);
    Hb[(k - 1) * 64] = make_double2(t1x, t1y);   // duplicate of H[0], dropped
    return k - 1;                                 // m hull points H[0..m-1]
}

// 4 lanes per instance: quad = (even,odd) pair x2 duplicate. Even lane
// hull(P), odd lane hull(P++T); lanes 2,3 of the quad repeat lanes 0,1 so
// the wave count doubles (2 waves/SIMD -> latency hiding). Intersection via
// convex boundary line-integral (Liang-Barsky per edge) as in r8.
__global__ __launch_bounds__(64)
void giou_kernel(const float* __restrict__ pred,
                 const float* __restrict__ target,
                 const float* __restrict__ weight,
                 double* __restrict__ ws,
                 int n) {
    __shared__ double2 Hs[16 * 64];   // per-thread hull, [slot][tid], 16 KB
    double2* Hb = &Hs[threadIdx.x];
    const int lane = threadIdx.x;
    const int odd = lane & 1;
    const int i0 = blockIdx.x * 16 + (lane >> 2);   // 16 instances per block
    const bool valid = i0 < n;
    const int i = valid ? i0 : (n > 0 ? n - 1 : 0);

    // ---- target (4 pts) ----
    double Tx[4], Ty[4];
    {
        const float4* tp = (const float4*)target + (size_t)i * 2;
        float4 t0 = tp[0], t1 = tp[1];
        Tx[0] = t0.x; Ty[0] = t0.y; Tx[1] = t0.z; Ty[1] = t0.w;
        Tx[2] = t1.x; Ty[2] = t1.y; Tx[3] = t1.z; Ty[3] = t1.w;
    }
    double saT = 0.5 * ((Tx[0] * Ty[1] - Tx[1] * Ty[0]) + (Tx[1] * Ty[2] - Tx[2] * Ty[1]) +
                        (Tx[2] * Ty[3] - Tx[3] * Ty[2]) + (Tx[3] * Ty[0] - Tx[0] * Ty[3]));
    double areaB = fabs(saT);
    bool rev = saT < 0.0;
    double tcx[4], tcy[4];   // CCW target
#pragma unroll
    for (int k = 0; k < 4; k++) {
        tcx[k] = rev ? Tx[3 - k] : Tx[k];
        tcy[k] = rev ? Ty[3 - k] : Ty[k];
    }

    // ---- 13-pt working set: P ++ (odd ? T : exact dups of P[0]) ----
    double X[13], Y[13];
    {
        const float2* pp = (const float2*)pred + (size_t)i * 9;
#pragma unroll
        for (int k = 0; k < 9; k++) { float2 v = pp[k]; X[k] = v.x; Y[k] = v.y; }
    }
#pragma unroll
    for (int k = 0; k < 4; k++) {
        X[9 + k] = odd ? Tx[k] : X[0];
        Y[9 + k] = odd ? Ty[k] : Y[0];
    }

    // ---- sort + chain hull (identical code both lanes) ----
    sortxy<13>(X, Y);
    int m = chain_hull<13>(X, Y, Hb);

    // ---- own hull area ----
    double area;
    {
        double2 h0 = Hb[0];
        double px = h0.x, py = h0.y, s = 0.0;
#pragma unroll 1
        for (int j = 1; j < m; j++) {
            double2 c = Hb[j * 64];
            s += px * c.y - c.x * py;
            px = c.x; py = c.y;
        }
        s += px * h0.y - h0.x * py;
        area = fabs(0.5 * s);
    }
    double other = __shfl_xor(area, 1, 64);
    double areaA = odd ? other : area;
    double areaC = odd ? area : other;
    int mo = __shfl_xor(m, 1, 64);
    const int mA = odd ? mo : m;            // this pair's hull(P) size
    __syncthreads();                         // partner hull visible in LDS
    const double2* HA = odd ? &Hs[lane - 1] : Hb;   // pair's hull(P)

    // ---- intersection boundary integral ----
    double S = 0.0;
    if (!odd) {
        // hullA edges clipped by T's 4 CCW half-planes (Liang-Barsky, exact)
#pragma unroll 1
        for (int j = 0; j < mA; j++) {
            double2 p = HA[j * 64];
            int j1 = (j + 1 == mA) ? 0 : j + 1;
            double2 q = HA[j1 * 64];
            double lo = 0.0, hi = 1.0;
#pragma unroll
            for (int e = 0; e < 4; e++) {
                double ax = tcx[e], ay = tcy[e];
                int e1 = (e + 1) & 3;
                double ex_ = tcx[e1] - ax, ey_ = tcy[e1] - ay;
                double s0 = ex_ * (p.y - ay) - ey_ * (p.x - ax);
                double s1 = ex_ * (q.y - ay) - ey_ * (q.x - ax);
                bool in0 = s0 >= 0.0, in1 = s1 >= 0.0;
                if (!in0 && !in1) { lo = 1.0; hi = 0.0; }
                else if (in0 != in1) {
                    double t = s0 / (s0 - s1);   // signs differ -> t in [0,1]
                    if (!in0) lo = fmax(lo, t); else hi = fmin(hi, t);
                }
            }
            if (lo < hi) {
                double dx_ = q.x - p.x, dy_ = q.y - p.y;
                double A0x = p.x + lo * dx_, A0y = p.y + lo * dy_;
                double B0x = p.x + hi * dx_, B0y = p.y + hi * dy_;
                S += A0x * B0y - B0x * A0y;
            }
        }
    } else if (mA >= 2) {
        // T's 4 edges clipped by hullA's half-planes
        double lo[4] = {0.0, 0.0, 0.0, 0.0}, hi[4] = {1.0, 1.0, 1.0, 1.0};
#pragma unroll 1
        for (int j = 0; j < mA; j++) {
            double2 a = HA[j * 64];
            int j1 = (j + 1 == mA) ? 0 : j + 1;
            double2 b = HA[j1 * 64];
            double ex_ = b.x - a.x, ey_ = b.y - a.y;
#pragma unroll
            for (int k = 0; k < 4; k++) {
                int k1 = (k + 1) & 3;
                double s0 = ex_ * (tcy[k] - a.y) - ey_ * (tcx[k] - a.x);
                double s1 = ex_ * (tcy[k1] - a.y) - ey_ * (tcx[k1] - a.x);
                bool in0 = s0 >= 0.0, in1 = s1 >= 0.0;
                if (!in0 && !in1) { lo[k] = 1.0; hi[k] = 0.0; }
                else if (in0 != in1) {
                    double t = s0 / (s0 - s1);
                    if (!in0) lo[k] = fmax(lo[k], t); else hi[k] = fmin(hi[k], t);
                }
            }
        }
#pragma unroll
        for (int k = 0; k < 4; k++) {
            if (lo[k] < hi[k]) {
                int k1 = (k + 1) & 3;
                double dx_ = tcx[k1] - tcx[k], dy_ = tcy[k1] - tcy[k];
                double A0x = tcx[k] + lo[k] * dx_, A0y = tcy[k] + lo[k] * dy_;
                double B0x = tcx[k] + hi[k] * dx_, B0y = tcy[k] + hi[k] * dy_;
                S += A0x * B0y - B0x * A0y;
            }
        }
    }
    double So = __shfl_xor(S, 1, 64);
    double inter = fabs(0.5 * (S + So));

    double uni = areaA + areaB - inter;
    double giou = inter / fmax(uni, EPSD) - (areaC - uni) / fmax(areaC, EPSD);
    double loss = (1.0 - giou) * (double)weight[i];
    // only one lane of each quad contributes (lanes 1-3 are dup/partner)
    double contrib = (((lane & 3) == 0) && valid) ? loss : 0.0;

    // ---- single-wave reduction -> per-block partial ----
#pragma unroll
    for (int off = 32; off > 0; off >>= 1) contrib += __shfl_down(contrib, off, 64);
    if (lane == 0) ws[blockIdx.x] = contrib;
}

__global__ __launch_bounds__(256)
void reduce_kernel(const double* __restrict__ ws, float* __restrict__ out,
                   int nb, double invN) {
    int t = threadIdx.x;
    double s = 0.0;
    for (int j = t; j < nb; j += 256) s += ws[j];
#pragma unroll
    for (int off = 32; off > 0; off >>= 1) s += __shfl_down(s, off, 64);
    __shared__ double red[4];
    if ((t & 63) == 0) red[t >> 6] = s;
    __syncthreads();
    if (t == 0) out[0] = (float)((red[0] + red[1] + red[2] + red[3]) * invN);
}

extern "C" void kernel_launch(void* const* d_in, const int* in_sizes, int n_in,
                              void* d_out, int out_size, void* d_ws, size_t ws_size,
                              hipStream_t stream) {
    const float* pred = (const float*)d_in[0];
    const float* target = (const float*)d_in[1];
    const float* weight = (const float*)d_in[2];
    float* out = (float*)d_out;
    double* ws = (double*)d_ws;
    int n = in_sizes[2];  // weight has N elements

    int grid = (n + 15) / 16;  // 16 instances per 64-thread block (lane quads)
    giou_kernel<<<grid, 64, 0, stream>>>(pred, target, weight, ws, n);
    reduce_kernel<<<1, 256, 0, stream>>>(ws, out, grid, 1.0 / (double)n);
}

// Round 10
// 78.538 us; speedup vs baseline: 1.0711x; 1.0711x over previous
//
#include <hip/hip_runtime.h>
#include <math.h>

#define EPSD 1e-9

// Lane pairs per instance: even lane marches hull(P) (P padded with 4 exact
// dups of P[0]); odd lane marches hull(P++T) for areaC. Intersection area via
// convex boundary line-integral (r8-validated): S1 = hull(P) edges clipped
// inside T, S2 = T edges clipped inside hull(P); both computed branchless on
// all lanes from registers.
__global__ __launch_bounds__(64)
void giou_kernel(const float* __restrict__ pred,
                 const float* __restrict__ target,
                 const float* __restrict__ weight,
                 double* __restrict__ ws,
                 int n) {
    __shared__ double2 Hs[13 * 64];           // [slot][tid], 13.3 KB
    double2* Hb = &Hs[threadIdx.x];
    const int lane = threadIdx.x;
    const int odd = lane & 1;
    const int i0 = blockIdx.x * 32 + (lane >> 1);
    const bool valid = i0 < n;
    const int i = valid ? i0 : (n > 0 ? n - 1 : 0);

    // ---- target (4 pts) ----
    double Tx[4], Ty[4];
    {
        const float4* tp = (const float4*)target + (size_t)i * 2;
        float4 t0 = tp[0], t1 = tp[1];
        Tx[0] = t0.x; Ty[0] = t0.y; Tx[1] = t0.z; Ty[1] = t0.w;
        Tx[2] = t1.x; Ty[2] = t1.y; Tx[3] = t1.z; Ty[3] = t1.w;
    }
    double saT = 0.5 * ((Tx[0] * Ty[1] - Tx[1] * Ty[0]) + (Tx[1] * Ty[2] - Tx[2] * Ty[1]) +
                        (Tx[2] * Ty[3] - Tx[3] * Ty[2]) + (Tx[3] * Ty[0] - Tx[0] * Ty[3]));
    double areaB = fabs(saT);
    bool rev = saT < 0.0;
    double tcx[4], tcy[4];    // CCW target
#pragma unroll
    for (int k = 0; k < 4; k++) {
        tcx[k] = rev ? Tx[3 - k] : Tx[k];
        tcy[k] = rev ? Ty[3 - k] : Ty[k];
    }

    // ---- 13-pt working set ----
    double X[13], Y[13];
    {
        const float2* pp = (const float2*)pred + (size_t)i * 9;
#pragma unroll
        for (int k = 0; k < 9; k++) { float2 v = pp[k]; X[k] = v.x; Y[k] = v.y; }
    }
#pragma unroll
    for (int k = 0; k < 4; k++) {
        X[9 + k] = odd ? Tx[k] : X[0];
        Y[9 + k] = odd ? Ty[k] : Y[0];
    }

    // ---- Jarvis march (CCW), <=13 uniform steps, inline area, write-only LDS ----
    double sxm = X[0], sym = Y[0];
#pragma unroll
    for (int j = 1; j < 13; j++) {
        bool lt = (X[j] < sxm) || ((X[j] == sxm) && (Y[j] < sym));
        sxm = lt ? X[j] : sxm;
        sym = lt ? Y[j] : sym;
    }
    double cx = sxm, cy = sym;
    double area2 = 0.0;
    int h = 0;
    bool done = false;
#pragma unroll 1
    for (int step = 0; step < 13; step++) {
        if (__builtin_amdgcn_ballot_w64(!done) == 0ull) break;   // wave-uniform early exit
        double bx = cx, by = cy;   // best == cur means "invalid"
        double db = 0.0;
#pragma unroll
        for (int j = 0; j < 13; j++) {
            double rx = X[j] - cx, ry = Y[j] - cy;
            double dc = rx * rx + ry * ry;           // ==0 -> cand is cur, skip
            double ox = bx - cx, oy = by - cy;
            double cr = ox * ry - oy * rx;           // <0: cand CW of best
            bool rep = (dc > 0.0) &&
                       ((db == 0.0) || (cr < 0.0) || ((cr == 0.0) && (dc > db)));
            bx = rep ? X[j] : bx;
            by = rep ? Y[j] : by;
            db = rep ? dc : db;
        }
        if (!done) {
            Hb[h * 64] = make_double2(cx, cy);
            h++;
            area2 += cx * by - bx * cy;
        }
        done = done || ((bx == sxm) && (by == sym)) || ((bx == cx) && (by == cy));
        cx = bx; cy = by;
    }
    double area = fabs(0.5 * area2);

    // ---- exchange, then batched readback of the pair's hull(P) ----
    double areaO = __shfl_xor(area, 1, 64);
    double areaA = odd ? areaO : area;
    double areaC = odd ? area : areaO;
    int hO = __shfl_xor(h, 1, 64);
    const int mA = odd ? hO : h;                // hull(P) vertex count (<=9)
    __syncthreads();
    const double2* HA = &Hs[lane & ~1];         // even column of the pair
    double hx[9], hy[9];
#pragma unroll
    for (int j = 0; j < 9; j++) {               // garbage beyond mA, gated below
        double2 v = HA[j * 64];
        hx[j] = v.x; hy[j] = v.y;
    }

    // ---- S1: hull(P) edges clipped inside T (4 CCW planes), branchless ----
    double S = 0.0;
#pragma unroll
    for (int j = 0; j < 9; j++) {
        bool real_ = (j < mA);
        bool wrapn = (j + 1 < mA);
        double qx_ = wrapn ? hx[(j + 1 < 9) ? j + 1 : 0] : hx[0];
        double qy_ = wrapn ? hy[(j + 1 < 9) ? j + 1 : 0] : hy[0];
        double px_ = hx[j], py_ = hy[j];
        double lo = 0.0, hi = 1.0;
#pragma unroll
        for (int e = 0; e < 4; e++) {
            int e1 = (e + 1) & 3;
            double ex_ = tcx[e1] - tcx[e], ey_ = tcy[e1] - tcy[e];
            double s0 = ex_ * (py_ - tcy[e]) - ey_ * (px_ - tcx[e]);
            double s1 = ex_ * (qy_ - tcy[e]) - ey_ * (qx_ - tcx[e]);
            bool in0 = s0 >= 0.0, in1 = s1 >= 0.0;
            double den = s0 - s1;
            double dd = (fabs(den) < 1e-300) ? 1e-300 : den;
            double t = s0 / dd;                  // only used when in0!=in1
            bool crs = (in0 != in1);
            lo = (crs && !in0) ? fmax(lo, t) : lo;
            hi = (crs && in0)  ? fmin(hi, t) : hi;
            bool out2 = (!in0 && !in1);
            lo = out2 ? 1.0 : lo;                // sticky kill
            hi = out2 ? 0.0 : hi;
        }
        double dxe = qx_ - px_, dye = qy_ - py_;
        double A0x = px_ + lo * dxe, A0y = py_ + lo * dye;
        double B0x = px_ + hi * dxe, B0y = py_ + hi * dye;
        double c_ = A0x * B0y - B0x * A0y;
        S += (real_ && (lo < hi)) ? c_ : 0.0;
    }

    // ---- S2: T edges clipped inside hull(P) (mA CCW planes), branchless ----
    double loT[4] = {0.0, 0.0, 0.0, 0.0}, hiT[4] = {1.0, 1.0, 1.0, 1.0};
#pragma unroll
    for (int j = 0; j < 9; j++) {
        bool pr = (j < mA);
        bool wrapn = (j + 1 < mA);
        double ax_ = hx[j], ay_ = hy[j];
        double bx_ = wrapn ? hx[(j + 1 < 9) ? j + 1 : 0] : hx[0];
        double by_ = wrapn ? hy[(j + 1 < 9) ? j + 1 : 0] : hy[0];
        double ex_ = bx_ - ax_, ey_ = by_ - ay_;
#pragma unroll
        for (int k = 0; k < 4; k++) {
            int k1 = (k + 1) & 3;
            double s0 = ex_ * (tcy[k] - ay_) - ey_ * (tcx[k] - ax_);
            double s1 = ex_ * (tcy[k1] - ay_) - ey_ * (tcx[k1] - ax_);
            bool in0 = s0 >= 0.0, in1 = s1 >= 0.0;
            double den = s0 - s1;
            double dd = (fabs(den) < 1e-300) ? 1e-300 : den;
            double t = s0 / dd;
            bool crs = (in0 != in1) && pr;
            loT[k] = (crs && !in0) ? fmax(loT[k], t) : loT[k];
            hiT[k] = (crs && in0)  ? fmin(hiT[k], t) : hiT[k];
            bool out2 = (!in0 && !in1) && pr;
            loT[k] = out2 ? 1.0 : loT[k];
            hiT[k] = out2 ? 0.0 : hiT[k];
        }
    }
    bool hullOK = (mA >= 3);                    // mA<3: inter == 0 exactly
#pragma unroll
    for (int k = 0; k < 4; k++) {
        int k1 = (k + 1) & 3;
        double dxe = tcx[k1] - tcx[k], dye = tcy[k1] - tcy[k];
        double A0x = tcx[k] + loT[k] * dxe, A0y = tcy[k] + loT[k] * dye;
        double B0x = tcx[k] + hiT[k] * dxe, B0y = tcy[k] + hiT[k] * dye;
        double c_ = A0x * B0y - B0x * A0y;
        S += ((loT[k] < hiT[k]) && hullOK) ? c_ : 0.0;
    }
    double inter = fabs(0.5 * S);

    double uni = areaA + areaB - inter;
    double giou = inter / fmax(uni, EPSD) - (areaC - uni) / fmax(areaC, EPSD);
    double loss = (1.0 - giou) * (double)weight[i];
    double contrib = (!odd && valid) ? loss : 0.0;

    // ---- single-wave reduction -> per-block partial ----
#pragma unroll
    for (int off = 32; off > 0; off >>= 1) contrib += __shfl_down(contrib, off, 64);
    if (lane == 0) ws[blockIdx.x] = contrib;
}

__global__ __launch_bounds__(256)
void reduce_kernel(const double* __restrict__ ws, float* __restrict__ out,
                   int nb, double invN) {
    int t = threadIdx.x;
    double s = 0.0;
    for (int j = t; j < nb; j += 256) s += ws[j];
#pragma unroll
    for (int off = 32; off > 0; off >>= 1) s += __shfl_down(s, off, 64);
    __shared__ double red[4];
    if ((t & 63) == 0) red[t >> 6] = s;
    __syncthreads();
    if (t == 0) out[0] = (float)((red[0] + red[1] + red[2] + red[3]) * invN);
}

extern "C" void kernel_launch(void* const* d_in, const int* in_sizes, int n_in,
                              void* d_out, int out_size, void* d_ws, size_t ws_size,
                              hipStream_t stream) {
    const float* pred = (const float*)d_in[0];
    const float* target = (const float*)d_in[1];
    const float* weight = (const float*)d_in[2];
    float* out = (float*)d_out;
    double* ws = (double*)d_ws;
    int n = in_sizes[2];  // weight has N elements

    int grid = (n + 31) / 32;  // 32 instances per 64-thread block (lane pairs)
    giou_kernel<<<grid, 64, 0, stream>>>(pred, target, weight, ws, n);
    reduce_kernel<<<1, 256, 0, stream>>>(ws, out, grid, 1.0 / (double)n);
}

// Round 11
// 75.533 us; speedup vs baseline: 1.1137x; 1.0398x over previous
//
#include <hip/hip_runtime.h>
#include <math.h>

#define EPSF 1e-9f

// Lane pairs per instance: even lane marches hull(P) (P padded with 4 exact
// dups of P[0]); odd lane marches hull(P++T) for areaC. Intersection area via
// convex boundary line-integral (r8/r10-validated): S1 = hull(P) edges clipped
// inside T, S2 = T edges clipped inside hull(P); branchless on all lanes.
// All geometry f32 on per-instance centered coordinates; final giou clamped
// to [-1,1] (true giou is always in (-1,1], so clamping only reduces error
// and bounds any f32-degenerate instance to error <= 2).
__global__ __launch_bounds__(64)
void giou_kernel(const float* __restrict__ pred,
                 const float* __restrict__ target,
                 const float* __restrict__ weight,
                 float* __restrict__ ws,
                 int n) {
    __shared__ float2 Hs[13 * 64];            // [slot][tid], 6.7 KB
    float2* Hb = &Hs[threadIdx.x];
    const int lane = threadIdx.x;
    const int odd = lane & 1;
    const int i0 = blockIdx.x * 32 + (lane >> 1);
    const bool valid = i0 < n;
    const int i = valid ? i0 : (n > 0 ? n - 1 : 0);

    // ---- target (4 pts) + instance centering at T centroid ----
    float Tx[4], Ty[4];
    {
        const float4* tp = (const float4*)target + (size_t)i * 2;
        float4 t0 = tp[0], t1 = tp[1];
        Tx[0] = t0.x; Ty[0] = t0.y; Tx[1] = t0.z; Ty[1] = t0.w;
        Tx[2] = t1.x; Ty[2] = t1.y; Tx[3] = t1.z; Ty[3] = t1.w;
    }
    float ctrx = 0.25f * (Tx[0] + Tx[1] + Tx[2] + Tx[3]);
    float ctry = 0.25f * (Ty[0] + Ty[1] + Ty[2] + Ty[3]);
#pragma unroll
    for (int k = 0; k < 4; k++) { Tx[k] -= ctrx; Ty[k] -= ctry; }

    float saT = 0.5f * ((Tx[0] * Ty[1] - Tx[1] * Ty[0]) + (Tx[1] * Ty[2] - Tx[2] * Ty[1]) +
                        (Tx[2] * Ty[3] - Tx[3] * Ty[2]) + (Tx[3] * Ty[0] - Tx[0] * Ty[3]));
    float areaB = fabsf(saT);
    bool rev = saT < 0.f;
    float tcx[4], tcy[4];     // CCW target (centered)
#pragma unroll
    for (int k = 0; k < 4; k++) {
        tcx[k] = rev ? Tx[3 - k] : Tx[k];
        tcy[k] = rev ? Ty[3 - k] : Ty[k];
    }

    // ---- 13-pt working set (centered) ----
    float X[13], Y[13];
    {
        const float2* pp = (const float2*)pred + (size_t)i * 9;
#pragma unroll
        for (int k = 0; k < 9; k++) {
            float2 v = pp[k];
            X[k] = v.x - ctrx; Y[k] = v.y - ctry;
        }
    }
#pragma unroll
    for (int k = 0; k < 4; k++) {
        X[9 + k] = odd ? Tx[k] : X[0];
        Y[9 + k] = odd ? Ty[k] : Y[0];
    }

    // ---- Jarvis march (CCW), <=13 uniform steps, inline area, write-only LDS ----
    float sxm = X[0], sym = Y[0];
#pragma unroll
    for (int j = 1; j < 13; j++) {
        bool lt = (X[j] < sxm) || ((X[j] == sxm) && (Y[j] < sym));
        sxm = lt ? X[j] : sxm;
        sym = lt ? Y[j] : sym;
    }
    float cx = sxm, cy = sym;
    float area2 = 0.f;
    int h = 0;
    bool done = false;
#pragma unroll 1
    for (int step = 0; step < 13; step++) {
        if (__builtin_amdgcn_ballot_w64(!done) == 0ull) break;   // wave-uniform exit
        float bx = cx, by = cy;   // best == cur means "invalid"
        float db = 0.f;
#pragma unroll
        for (int j = 0; j < 13; j++) {
            float rx = X[j] - cx, ry = Y[j] - cy;
            float dc = rx * rx + ry * ry;            // ==0 -> cand is cur, skip
            float ox = bx - cx, oy = by - cy;
            float cr = ox * ry - oy * rx;            // <0: cand CW of best
            bool rep = (dc > 0.f) &&
                       ((db == 0.f) || (cr < 0.f) || ((cr == 0.f) && (dc > db)));
            bx = rep ? X[j] : bx;
            by = rep ? Y[j] : by;
            db = rep ? dc : db;
        }
        if (!done) {
            Hb[h * 64] = make_float2(cx, cy);
            h++;
            area2 += cx * by - bx * cy;
        }
        done = done || ((bx == sxm) && (by == sym)) || ((bx == cx) && (by == cy));
        cx = bx; cy = by;
    }
    float area = fabsf(0.5f * area2);

    // ---- exchange, then batched readback of the pair's hull(P) ----
    float areaO = __shfl_xor(area, 1, 64);
    float areaA = odd ? areaO : area;
    float areaC = odd ? area : areaO;
    int hO = __shfl_xor(h, 1, 64);
    const int mA = odd ? hO : h;                // hull(P) vertex count (<=9)
    __syncthreads();
    const float2* HA = &Hs[lane & ~1];          // even column of the pair
    float hx[9], hy[9];
#pragma unroll
    for (int j = 0; j < 9; j++) {               // garbage beyond mA, gated below
        float2 v = HA[j * 64];
        hx[j] = v.x; hy[j] = v.y;
    }

    // ---- S1: hull(P) edges clipped inside T (4 CCW planes), branchless ----
    float S = 0.f;
#pragma unroll
    for (int j = 0; j < 9; j++) {
        bool real_ = (j < mA);
        bool wrapn = (j + 1 < mA);
        float qx_ = wrapn ? hx[(j + 1 < 9) ? j + 1 : 0] : hx[0];
        float qy_ = wrapn ? hy[(j + 1 < 9) ? j + 1 : 0] : hy[0];
        float px_ = hx[j], py_ = hy[j];
        float lo = 0.f, hi = 1.f;
#pragma unroll
        for (int e = 0; e < 4; e++) {
            int e1 = (e + 1) & 3;
            float ex_ = tcx[e1] - tcx[e], ey_ = tcy[e1] - tcy[e];
            float s0 = ex_ * (py_ - tcy[e]) - ey_ * (px_ - tcx[e]);
            float s1 = ex_ * (qy_ - tcy[e]) - ey_ * (qx_ - tcx[e]);
            bool in0 = s0 >= 0.f, in1 = s1 >= 0.f;
            float den = s0 - s1;
            float dd = (fabsf(den) < 1e-30f) ? 1e-30f : den;
            float t = s0 / dd;                   // only used when in0!=in1
            bool crs = (in0 != in1);
            lo = (crs && !in0) ? fmaxf(lo, t) : lo;
            hi = (crs && in0)  ? fminf(hi, t) : hi;
            bool out2 = (!in0 && !in1);
            lo = out2 ? 1.f : lo;                // sticky kill
            hi = out2 ? 0.f : hi;
        }
        float dxe = qx_ - px_, dye = qy_ - py_;
        float A0x = px_ + lo * dxe, A0y = py_ + lo * dye;
        float B0x = px_ + hi * dxe, B0y = py_ + hi * dye;
        float c_ = A0x * B0y - B0x * A0y;
        S += (real_ && (lo < hi)) ? c_ : 0.f;
    }

    // ---- S2: T edges clipped inside hull(P) (mA CCW planes), branchless ----
    float loT[4] = {0.f, 0.f, 0.f, 0.f}, hiT[4] = {1.f, 1.f, 1.f, 1.f};
#pragma unroll
    for (int j = 0; j < 9; j++) {
        bool pr = (j < mA);
        bool wrapn = (j + 1 < mA);
        float ax_ = hx[j], ay_ = hy[j];
        float bx_ = wrapn ? hx[(j + 1 < 9) ? j + 1 : 0] : hx[0];
        float by_ = wrapn ? hy[(j + 1 < 9) ? j + 1 : 0] : hy[0];
        float ex_ = bx_ - ax_, ey_ = by_ - ay_;
#pragma unroll
        for (int k = 0; k < 4; k++) {
            int k1 = (k + 1) & 3;
            float s0 = ex_ * (tcy[k] - ay_) - ey_ * (tcx[k] - ax_);
            float s1 = ex_ * (tcy[k1] - ay_) - ey_ * (tcx[k1] - ax_);
            bool in0 = s0 >= 0.f, in1 = s1 >= 0.f;
            float den = s0 - s1;
            float dd = (fabsf(den) < 1e-30f) ? 1e-30f : den;
            float t = s0 / dd;
            bool crs = (in0 != in1) && pr;
            loT[k] = (crs && !in0) ? fmaxf(loT[k], t) : loT[k];
            hiT[k] = (crs && in0)  ? fminf(hiT[k], t) : hiT[k];
            bool out2 = (!in0 && !in1) && pr;
            loT[k] = out2 ? 1.f : loT[k];
            hiT[k] = out2 ? 0.f : hiT[k];
        }
    }
    bool hullOK = (mA >= 3);                    // mA<3: inter == 0 exactly
#pragma unroll
    for (int k = 0; k < 4; k++) {
        int k1 = (k + 1) & 3;
        float dxe = tcx[k1] - tcx[k], dye = tcy[k1] - tcy[k];
        float A0x = tcx[k] + loT[k] * dxe, A0y = tcy[k] + loT[k] * dye;
        float B0x = tcx[k] + hiT[k] * dxe, B0y = tcy[k] + hiT[k] * dye;
        float c_ = A0x * B0y - B0x * A0y;
        S += ((loT[k] < hiT[k]) && hullOK) ? c_ : 0.f;
    }
    float inter = fabsf(0.5f * S);

    float uni = areaA + areaB - inter;
    float giou = inter / fmaxf(uni, EPSF) - (areaC - uni) / fmaxf(areaC, EPSF);
    giou = fminf(1.f, fmaxf(-1.f, giou));   // true giou in (-1,1]: clamp only helps
    float loss = (1.f - giou) * weight[i];
    float contrib = (!odd && valid) ? loss : 0.f;

    // ---- single-wave reduction -> per-block partial ----
#pragma unroll
    for (int off = 32; off > 0; off >>= 1) contrib += __shfl_down(contrib, off, 64);
    if (lane == 0) ws[blockIdx.x] = contrib;
}

__global__ __launch_bounds__(256)
void reduce_kernel(const float* __restrict__ ws, float* __restrict__ out,
                   int nb, double invN) {
    int t = threadIdx.x;
    double s = 0.0;
    for (int j = t; j < nb; j += 256) s += (double)ws[j];
#pragma unroll
    for (int off = 32; off > 0; off >>= 1) s += __shfl_down(s, off, 64);
    __shared__ double red[4];
    if ((t & 63) == 0) red[t >> 6] = s;
    __syncthreads();
    if (t == 0) out[0] = (float)((red[0] + red[1] + red[2] + red[3]) * invN);
}

extern "C" void kernel_launch(void* const* d_in, const int* in_sizes, int n_in,
                              void* d_out, int out_size, void* d_ws, size_t ws_size,
                              hipStream_t stream) {
    const float* pred = (const float*)d_in[0];
    const float* target = (const float*)d_in[1];
    const float* weight = (const float*)d_in[2];
    float* out = (float*)d_out;
    float* ws = (float*)d_ws;
    int n = in_sizes[2];  // weight has N elements

    int grid = (n + 31) / 32;  // 32 instances per 64-thread block (lane pairs)
    giou_kernel<<<grid, 64, 0, stream>>>(pred, target, weight, ws, n);
    reduce_kernel<<<1, 256, 0, stream>>>(ws, out, grid, 1.0 / (double)n);
}